// Round 17
// baseline (1531.280 us; speedup 1.0000x reference)
//
#include <hip/hip_runtime.h>

#define T_SEQ 2048
#define DMODEL 2048
#define NH 16
#define NKV 4
#define HD 128
#define ISZ 5632
#define BATCH 2
#define QKS 2560   // q|k row stride in qkbuf
#define QKVN 3072  // fused q|k|v GEMM width

typedef unsigned short ushort_t;
typedef __attribute__((ext_vector_type(8))) short short8;
typedef __attribute__((ext_vector_type(4))) float f32x4;

__device__ __forceinline__ ushort_t f2bf(float f) {
  unsigned int u = __float_as_uint(f);
  unsigned int r = (u + 0x7FFFu + ((u >> 16) & 1u)) >> 16;
  return (ushort_t)r;
}
__device__ __forceinline__ float bf2f(ushort_t h) {
  return __uint_as_float(((unsigned int)h) << 16);
}

// ---------------- weight fp32 (K,N) -> bf16 transposed (N,K) ----------------
__global__ __launch_bounds__(256) void wconv_kernel(const float* __restrict__ W,
                                                    ushort_t* __restrict__ Wt,
                                                    int K, int N) {
  __shared__ float tile[32][33];
  const int n0 = blockIdx.x * 32, k0 = blockIdx.y * 32;
  const int t = threadIdx.x;
  const int r = t >> 3, c = (t & 7) * 4;
  float4 v = *(const float4*)(W + (size_t)(k0 + r) * N + n0 + c);
  tile[r][c + 0] = v.x; tile[r][c + 1] = v.y; tile[r][c + 2] = v.z; tile[r][c + 3] = v.w;
  __syncthreads();
  ushort4 o;
  o.x = f2bf(tile[c + 0][r]);
  o.y = f2bf(tile[c + 1][r]);
  o.z = f2bf(tile[c + 2][r]);
  o.w = f2bf(tile[c + 3][r]);
  *(ushort4*)(Wt + (size_t)(n0 + r) * K + k0 + c) = o;
}

// ---- w1 variant: output rows permuted to interleave gate/up in 16-col groups ----
__global__ __launch_bounds__(256) void wconvP_kernel(const float* __restrict__ W,
                                                     ushort_t* __restrict__ Wt,
                                                     int K, int N) {
  __shared__ float tile[32][33];
  const int n0 = blockIdx.x * 32, k0 = blockIdx.y * 32;
  const int t = threadIdx.x;
  const int r = t >> 3, c = (t & 7) * 4;
  float4 v = *(const float4*)(W + (size_t)(k0 + r) * N + n0 + c);
  tile[r][c + 0] = v.x; tile[r][c + 1] = v.y; tile[r][c + 2] = v.z; tile[r][c + 3] = v.w;
  __syncthreads();
  ushort4 o;
  o.x = f2bf(tile[c + 0][r]);
  o.y = f2bf(tile[c + 1][r]);
  o.z = f2bf(tile[c + 2][r]);
  o.w = f2bf(tile[c + 3][r]);
  int n = n0 + r;
  int np = (n < ISZ) ? ((n >> 4) << 5) + (n & 15)
                     : (((n - ISZ) >> 4) << 5) + 16 + ((n - ISZ) & 15);
  *(ushort4*)(Wt + (size_t)np * K + k0 + c) = o;
}

__global__ __launch_bounds__(256) void catbias_kernel(const float* __restrict__ a,
                                                      const float* __restrict__ b,
                                                      const float* __restrict__ c,
                                                      float* __restrict__ o) {
  int i = blockIdx.x * 256 + threadIdx.x;
  if (i < QKVN) o[i] = (i < 2048) ? a[i] : (i < QKS) ? b[i - 2048] : c[i - QKS];
}

// ---------------- RMSNorm (f32 in, bf16 out), D = 2048, block = 256 ----------------
__global__ __launch_bounds__(256) void rmsnorm_kernel(const float* __restrict__ x,
                                                      const float* __restrict__ w,
                                                      ushort_t* __restrict__ out) {
  const int row = blockIdx.x;
  const int t = threadIdx.x;
  const float* xr = x + (size_t)row * DMODEL;
  float4 v0 = *(const float4*)(xr + t * 4);
  float4 v1 = *(const float4*)(xr + 1024 + t * 4);
  float ss = v0.x * v0.x + v0.y * v0.y + v0.z * v0.z + v0.w * v0.w +
             v1.x * v1.x + v1.y * v1.y + v1.z * v1.z + v1.w * v1.w;
  #pragma unroll
  for (int m = 1; m < 64; m <<= 1) ss += __shfl_xor(ss, m);
  __shared__ float red[4];
  if ((t & 63) == 0) red[t >> 6] = ss;
  __syncthreads();
  float tot = red[0] + red[1] + red[2] + red[3];
  float rinv = rsqrtf(tot * (1.0f / DMODEL) + 1e-5f);
  float4 w0 = *(const float4*)(w + t * 4);
  float4 w1 = *(const float4*)(w + 1024 + t * 4);
  ushort4 o0, o1;
  o0.x = f2bf(v0.x * rinv * w0.x); o0.y = f2bf(v0.y * rinv * w0.y);
  o0.z = f2bf(v0.z * rinv * w0.z); o0.w = f2bf(v0.w * rinv * w0.w);
  o1.x = f2bf(v1.x * rinv * w1.x); o1.y = f2bf(v1.y * rinv * w1.y);
  o1.z = f2bf(v1.z * rinv * w1.z); o1.w = f2bf(v1.w * rinv * w1.w);
  *(ushort4*)(out + (size_t)row * DMODEL + t * 4) = o0;
  *(ushort4*)(out + (size_t)row * DMODEL + 1024 + t * 4) = o1;
}

// ================= 256x256 GEMM, double-buffered free-running pipeline ==================
// Wave-parity staggered quadrant order: even waves Q00,Q01,Q10,Q11; odd waves Q11,Q10,Q01,Q00.
// MODE 0: bf16 out.  MODE 2: QKV (rope q|k + V^T).  MODE 3: W1+SwiGLU (permuted gate/up).
template <int MODE>
__global__ __launch_bounds__(512, 2)
void gemm256_kernel(const ushort_t* __restrict__ A, int lda,
                    const ushort_t* __restrict__ Bt,
                    const float* __restrict__ bias, void* __restrict__ outp,
                    int M, int N, int K,
                    const float* __restrict__ rc, const float* __restrict__ rs,
                    ushort_t* __restrict__ outp2) {
  __shared__ ushort_t lds[65536];  // 128 KiB = 2 bufs x 64KB
  const int tid = threadIdx.x;
  const int wid = tid >> 6, lane = tid & 63;
  const int lq = lane & 15, g = lane >> 4;
  const int wm = wid >> 2, wn = wid & 3;
  const int m0 = (MODE == 2 ? blockIdx.x : blockIdx.y) * 256;
  const int n0 = (MODE == 2 ? blockIdx.y : blockIdx.x) * 256;
  const int NT = K >> 6;

  const char* ldsc = (const char*)lds;
  const int c0 = ((g ^ (lq & 3)) << 4) | (((lq >> 2) & 1) << 6);
  const int rbA = wm * 8192 + lq * 128 + c0;
  const int rbAx = rbA ^ 64;
  const int rbB = 32768 + wn * 4096 + lq * 128 + c0;
  const int rbBx = rbB ^ 64;

  const int l3 = lane >> 3;
  const int clog = ((lane & 7) ^ l3) << 4;
  const int s0 = wid * 16 + l3, s1 = s0 + 8;
  const int rA0 = (s0 & 63) + ((s0 >> 6) << 7);
  const int rA0b = (s1 & 63) + ((s1 >> 6) << 7);
  const int rB0 = ((s0 >> 5) << 6) + (s0 & 31);
  const int rB0b = ((s1 >> 5) << 6) + (s1 & 31);
  const char* pA0a = (const char*)A + (size_t)(m0 + rA0) * (lda * 2) + clog;
  const char* pA0b = (const char*)A + (size_t)(m0 + rA0b) * (lda * 2) + clog;
  const char* pA1a = pA0a + (size_t)64 * (lda * 2);
  const char* pA1b = pA0b + (size_t)64 * (lda * 2);
  const char* pB0a = (const char*)Bt + (size_t)(n0 + rB0) * (K * 2) + clog;
  const char* pB0b = (const char*)Bt + (size_t)(n0 + rB0b) * (K * 2) + clog;
  const char* pB1a = pB0a + (size_t)32 * (K * 2);
  const char* pB1b = pB0b + (size_t)32 * (K * 2);
  ushort_t* sd = lds + wid * 1024;

#define GLL(SRC, DOFF)                                                        \
  __builtin_amdgcn_global_load_lds(                                           \
      (const __attribute__((address_space(1))) void*)(SRC),                   \
      (__attribute__((address_space(3))) void*)(sd + (DOFF)), 16, 0, 0)
#define STG_ALL(PB)                                                           \
  {                                                                           \
    GLL(pA0a, (PB)*32768 + 0);     GLL(pA0b, (PB)*32768 + 512);               \
    GLL(pB0a, (PB)*32768 + 16384); GLL(pB0b, (PB)*32768 + 16896);             \
    GLL(pB1a, (PB)*32768 + 24576); GLL(pB1b, (PB)*32768 + 25088);             \
    GLL(pA1a, (PB)*32768 + 8192);  GLL(pA1b, (PB)*32768 + 8704);              \
    pA0a += 128; pA0b += 128; pA1a += 128; pA1b += 128;                       \
    pB0a += 128; pB0b += 128; pB1a += 128; pB1b += 128;                       \
  }

  f32x4 acc[8][4] = {};

#define RDA(P, H, DST)                                                        \
    _Pragma("unroll") for (int mi = 0; mi < 4; ++mi) {                        \
      DST[mi][0] = *(const short8*)(ldsc + (P)*65536 + rbA + (H)*16384 + mi * 2048);  \
      DST[mi][1] = *(const short8*)(ldsc + (P)*65536 + rbAx + (H)*16384 + mi * 2048); \
    }
#define RDB(P, H, DST)                                                        \
    _Pragma("unroll") for (int nj = 0; nj < 2; ++nj) {                        \
      DST[nj][0] = *(const short8*)(ldsc + (P)*65536 + rbB + (H)*16384 + nj * 2048);  \
      DST[nj][1] = *(const short8*)(ldsc + (P)*65536 + rbBx + (H)*16384 + nj * 2048); \
    }
#define MM(AH, BH, ASRC, BSRC)                                                \
    _Pragma("unroll") for (int mi = 0; mi < 4; ++mi)                          \
      _Pragma("unroll") for (int nj = 0; nj < 2; ++nj) {                      \
        acc[(AH)*4 + mi][(BH)*2 + nj] = __builtin_amdgcn_mfma_f32_16x16x32_bf16(ASRC[mi][0], BSRC[nj][0], acc[(AH)*4 + mi][(BH)*2 + nj], 0, 0, 0); \
        acc[(AH)*4 + mi][(BH)*2 + nj] = __builtin_amdgcn_mfma_f32_16x16x32_bf16(ASRC[mi][1], BSRC[nj][1], acc[(AH)*4 + mi][(BH)*2 + nj], 0, 0, 0); \
      }
#define TILE_F(P, F, DOST)                                                    \
  {                                                                           \
    asm volatile("s_waitcnt vmcnt(0)" ::: "memory");                          \
    __builtin_amdgcn_s_barrier();                                             \
    if (DOST) STG_ALL((P) ^ 1)                                                \
    short8 aF[4][2], aS[4][2], bF[2][2], bS[2][2];                            \
    RDA(P, F, aF)                                                             \
    RDB(P, F, bF)                                                             \
    MM(F, F, aF, bF)                                                          \
    RDB(P, 1 - (F), bS)                                                       \
    MM(F, 1 - (F), aF, bS)                                                    \
    RDA(P, 1 - (F), aS)                                                       \
    MM(1 - (F), F, aS, bF)                                                    \
    MM(1 - (F), 1 - (F), aS, bS)                                              \
  }
#define TILE(P, DOST)                                                         \
  {                                                                           \
    if ((wid & 1) == 0) TILE_F(P, 0, DOST) else TILE_F(P, 1, DOST)            \
  }

  STG_ALL(0)
  for (int it = 0; it + 2 < NT; it += 2) {
    TILE(0, true)
    TILE(1, true)
  }
  TILE(0, true)
  TILE(1, false)
#undef TILE
#undef TILE_F
#undef MM
#undef RDB
#undef RDA
#undef GLL
#undef STG_ALL

  if (MODE == 3) {
    #pragma unroll
    for (int nf = 0; nf < 4; nf += 2) {
      int cg = n0 + wn * 64 + nf * 16 + lq;    // permuted gate col
      int G = ((cg >> 5) << 4) | (cg & 15);    // original gate index (= act col)
      float bg = bias[G];
      float bu = bias[ISZ + G];
      #pragma unroll
      for (int mf = 0; mf < 8; ++mf) {
        #pragma unroll
        for (int i = 0; i < 4; ++i) {
          int r = m0 + wm * 128 + mf * 16 + g * 4 + i;
          float gv = acc[mf][nf][i] + bg;
          float uv = acc[mf][nf + 1][i] + bu;
          float sl = gv / (1.f + __expf(-gv));
          ((ushort_t*)outp)[(size_t)r * ISZ + G] = f2bf(sl * uv);
        }
      }
    }
  } else {
    #pragma unroll
    for (int nf = 0; nf < 4; ++nf) {
      int c = n0 + wn * 64 + nf * 16 + lq;
      float bb = bias[c];
      int d = (c & (HD - 1)) >> 1;
      #pragma unroll
      for (int mf = 0; mf < 8; ++mf) {
        #pragma unroll
        for (int i = 0; i < 4; ++i) {
          int r = m0 + wm * 128 + mf * 16 + g * 4 + i;
          float av = acc[mf][nf][i] + bb;
          if (MODE == 2) {
            if (c < QKS) {
              float pr = __shfl_xor(av, 1);
              int t = r & (T_SEQ - 1);
              float co = rc[t * 64 + d];
              float si = rs[t * 64 + d];
              float ov = (lq & 1) ? (pr * si + av * co) : (av * co - pr * si);
              ((ushort_t*)outp)[(size_t)r * QKS + c] = f2bf(ov);
            } else {
              int cv = c - QKS;
              int hk = cv >> 7, dd = cv & (HD - 1);
              int b2 = r >> 11, t2 = r & (T_SEQ - 1);
              outp2[((size_t)(b2 * NKV + hk) * HD + dd) * T_SEQ + t2] = f2bf(av);
            }
          } else {
            ((ushort_t*)outp)[(size_t)r * N + c] = f2bf(av);
          }
        }
      }
    }
  }
}

// ================= 128x256 GEMM (8 waves, 64x64 wave-tiles), f32 res-add epilogue ========
// Wave-parity staggered: even waves mi 0-1 then 2-3, odd waves reversed.
__global__ __launch_bounds__(512, 1)
void gemm128_kernel(const ushort_t* __restrict__ A, int lda,
                    const ushort_t* __restrict__ Bt,
                    const float* __restrict__ bias, const float* __restrict__ res,
                    float* __restrict__ outp, int M, int N, int K) {
  __shared__ ushort_t lds[49152];  // 96KB = 2 bufs x 48KB
  const int tid = threadIdx.x;
  const int wid = tid >> 6, lane = tid & 63;
  const int lq = lane & 15, g = lane >> 4;
  const int wm = wid & 1, wn = wid >> 1;
  const int m0 = blockIdx.x * 128, n0 = blockIdx.y * 256;
  const int NT = K >> 6;

  const char* ldsc = (const char*)lds;
  const int c0 = ((g ^ (lq & 3)) << 4) | (((lq >> 2) & 1) << 6);
  const int rbA = wm * 8192 + lq * 128 + c0;
  const int rbAx = rbA ^ 64;
  const int rbB = 16384 + wn * 8192 + lq * 128 + c0;
  const int rbBx = rbB ^ 64;

  const char* pA[2];
  const char* pB[4];
  #pragma unroll
  for (int j = 0; j < 2; ++j) {
    int pb = (wid * 2 + j) * 1024 + lane * 16;
    int ob = pb ^ (((pb >> 7) & 7) << 4);
    pA[j] = (const char*)A + (size_t)(m0 + (ob >> 7)) * (lda * 2) + (ob & 127);
  }
  #pragma unroll
  for (int j = 0; j < 4; ++j) {
    int pb = (wid * 4 + j) * 1024 + lane * 16;
    int ob = pb ^ (((pb >> 7) & 7) << 4);
    pB[j] = (const char*)Bt + (size_t)(n0 + (ob >> 7)) * (K * 2) + (ob & 127);
  }
  ushort_t* sdA = lds + wid * 1024;
  ushort_t* sdB = lds + 8192 + wid * 2048;

#define GLL1(SRC, DST)                                                        \
  __builtin_amdgcn_global_load_lds(                                           \
      (const __attribute__((address_space(1))) void*)(SRC),                   \
      (__attribute__((address_space(3))) void*)(DST), 16, 0, 0)
#define STG128(PB)                                                            \
  {                                                                           \
    GLL1(pA[0], sdA + (PB)*24576 + 0);   GLL1(pA[1], sdA + (PB)*24576 + 512); \
    GLL1(pB[0], sdB + (PB)*24576 + 0);   GLL1(pB[1], sdB + (PB)*24576 + 512); \
    GLL1(pB[2], sdB + (PB)*24576 + 1024); GLL1(pB[3], sdB + (PB)*24576 + 1536); \
    pA[0] += 128; pA[1] += 128;                                               \
    pB[0] += 128; pB[1] += 128; pB[2] += 128; pB[3] += 128;                   \
  }

  f32x4 acc[4][4] = {};

#define RDA2(P, MI0, DST)                                                     \
    _Pragma("unroll") for (int q = 0; q < 2; ++q) {                           \
      DST[q][0] = *(const short8*)(ldsc + (P)*49152 + rbA + ((MI0) + q) * 2048);  \
      DST[q][1] = *(const short8*)(ldsc + (P)*49152 + rbAx + ((MI0) + q) * 2048); \
    }
#define RDB4(P, DST)                                                          \
    _Pragma("unroll") for (int nj = 0; nj < 4; ++nj) {                        \
      DST[nj][0] = *(const short8*)(ldsc + (P)*49152 + rbB + nj * 2048);      \
      DST[nj][1] = *(const short8*)(ldsc + (P)*49152 + rbBx + nj * 2048);     \
    }
#define MM128(MI0, ASRC, BSRC)                                                \
    _Pragma("unroll") for (int q = 0; q < 2; ++q)                             \
      _Pragma("unroll") for (int nj = 0; nj < 4; ++nj) {                      \
        acc[(MI0) + q][nj] = __builtin_amdgcn_mfma_f32_16x16x32_bf16(ASRC[q][0], BSRC[nj][0], acc[(MI0) + q][nj], 0, 0, 0); \
        acc[(MI0) + q][nj] = __builtin_amdgcn_mfma_f32_16x16x32_bf16(ASRC[q][1], BSRC[nj][1], acc[(MI0) + q][nj], 0, 0, 0); \
      }
#define TILE128_F(P, F2, TCUR)                                                \
  {                                                                           \
    asm volatile("s_waitcnt vmcnt(0)" ::: "memory");                          \
    __builtin_amdgcn_s_barrier();                                             \
    if ((TCUR) + 1 < NT) STG128((P) ^ 1)                                      \
    short8 aF[2][2], aS[2][2], bb[4][2];                                      \
    RDA2(P, F2, aF)                                                           \
    RDB4(P, bb)                                                               \
    MM128(F2, aF, bb)                                                         \
    RDA2(P, 2 - (F2), aS)                                                     \
    MM128(2 - (F2), aS, bb)                                                   \
  }
#define TILE128(P, TCUR)                                                      \
  {                                                                           \
    if ((wid & 1) == 0) TILE128_F(P, 0, TCUR) else TILE128_F(P, 2, TCUR)      \
  }

  STG128(0)
  for (int t = 0; t < NT; t += 2) {
    TILE128(0, t)
    TILE128(1, t + 1)
  }
#undef TILE128
#undef TILE128_F
#undef MM128
#undef RDB4
#undef RDA2
#undef GLL1
#undef STG128

  #pragma unroll
  for (int nf = 0; nf < 4; ++nf) {
    int c = n0 + wn * 64 + nf * 16 + lq;
    float bb = bias[c];
    #pragma unroll
    for (int mf = 0; mf < 4; ++mf) {
      #pragma unroll
      for (int i = 0; i < 4; ++i) {
        int r = m0 + wm * 64 + mf * 16 + g * 4 + i;
        size_t oidx = (size_t)r * N + c;
        outp[oidx] = res[oidx] + acc[mf][nf][i] + bb;
      }
    }
  }
}

// ---------------- Flash attention, GQA causal, QB=128, GLL-staged swizzled K/V ----------
#define QB 128
#define KB 64
#define PSTR 72

__global__ __launch_bounds__(256, 2)
void attn_kernel(const ushort_t* __restrict__ qk, const ushort_t* __restrict__ vT,
                 ushort_t* __restrict__ ao) {
  __shared__ ushort_t Klds[KB * 128];
  __shared__ ushort_t Vlds[HD * 64];
  __shared__ ushort_t Plds[4][16 * PSTR];

  const int tid = threadIdx.x;
  const int w = tid >> 6, lane = tid & 63;
  const int lq = lane & 15, g = lane >> 4;
  const int nqb = T_SEQ / QB;  // 16
  const int xq = blockIdx.x;
  const int qi = (xq & 1) ? (nqb - 1 - (xq >> 1)) : (xq >> 1);
  const int qb = qi * QB;
  const int h = blockIdx.y;
  const int b = blockIdx.z;
  const int hkv = h >> 2;
  const float scale = 0.08838834764831845f;

  short8 qf[2][4];
  #pragma unroll
  for (int gi = 0; gi < 2; ++gi) {
    const ushort_t* qrow = qk + ((size_t)(b * T_SEQ + qb + gi * 64 + w * 16 + lq) * QKS) + h * HD;
    #pragma unroll
    for (int ks = 0; ks < 4; ++ks) qf[gi][ks] = *(const short8*)(qrow + ks * 32 + g * 8);
  }

  f32x4 of[2][8] = {};
  float m_run[2] = {-1e30f, -1e30f};
  float l_run[2] = {0.f, 0.f};

  const char* kbaseC = (const char*)(qk + (size_t)b * T_SEQ * QKS + 2048 + hkv * HD);
  const char* vbaseC = (const char*)(vT + (size_t)(b * NKV + hkv) * HD * T_SEQ);
  const char* pK[4];
  const char* pV[4];
  #pragma unroll
  for (int j = 0; j < 4; ++j) {
    int krow = w * 16 + j * 4 + (lane >> 4);
    int kcol = ((lane & 15) * 16) ^ ((krow & 7) << 4);
    pK[j] = kbaseC + (size_t)krow * (QKS * 2) + kcol;
    int vrow = w * 32 + j * 8 + (lane >> 3);
    int vcol = ((lane & 7) * 16) ^ ((vrow & 7) << 4);
    pV[j] = vbaseC + (size_t)vrow * (T_SEQ * 2) + vcol;
  }
  ushort_t* kdst = Klds + w * 2048;
  ushort_t* vdst = Vlds + w * 2048;
  const char* kldsC = (const char*)Klds;
  const char* vldsC = (const char*)Vlds;

#define AGLL(SRC, DST)                                                        \
  __builtin_amdgcn_global_load_lds(                                           \
      (const __attribute__((address_space(1))) void*)(SRC),                   \
      (__attribute__((address_space(3))) void*)(DST), 16, 0, 0)

  const int nt = qb / KB + 2;
  for (int ti = 0; ti < nt; ++ti) {
    const int kt = ti * KB;
    #pragma unroll
    for (int j = 0; j < 4; ++j) {
      AGLL(pK[j], kdst + j * 512);
      AGLL(pV[j], vdst + j * 512);
      pK[j] += (size_t)KB * (QKS * 2);
      pV[j] += KB * 2;
    }
    asm volatile("s_waitcnt vmcnt(0)" ::: "memory");
    __builtin_amdgcn_s_barrier();

    #pragma unroll
    for (int gi = 0; gi < 2; ++gi) {
      const int qw = qb + gi * 64 + w * 16;
      if (kt <= qw + 15) {
        f32x4 s[4] = {};
        __builtin_amdgcn_s_setprio(1);
        #pragma unroll
        for (int c = 0; c < 4; ++c) {
          int krow = c * 16 + lq;
          #pragma unroll
          for (int ks = 0; ks < 4; ++ks) {
            short8 kf = *(const short8*)(kldsC + krow * 256 + (((ks * 64) + g * 16) ^ ((krow & 7) << 4)));
            s[c] = __builtin_amdgcn_mfma_f32_16x16x32_bf16(kf, qf[gi][ks], s[c], 0, 0, 0);
          }
        }
        __builtin_amdgcn_s_setprio(0);
        const int qg = qw + lq;
        float sv[16];
        #pragma unroll
        for (int c = 0; c < 4; ++c)
          #pragma unroll
          for (int i = 0; i < 4; ++i) {
            int kvg = kt + c * 16 + 4 * g + i;
            float xx = s[c][i] * scale;
            sv[c * 4 + i] = (kvg > qg) ? -1e30f : xx;
          }
        float tmax = sv[0];
        #pragma unroll
        for (int j = 1; j < 16; ++j) tmax = fmaxf(tmax, sv[j]);
        tmax = fmaxf(tmax, __shfl_xor(tmax, 16));
        tmax = fmaxf(tmax, __shfl_xor(tmax, 32));
        float mnew = fmaxf(m_run[gi], tmax);
        float corr = __expf(m_run[gi] - mnew);
        float pv[16];
        float ps = 0.f;
        #pragma unroll
        for (int j = 0; j < 16; ++j) { pv[j] = __expf(sv[j] - mnew); ps += pv[j]; }
        ps += __shfl_xor(ps, 16);
        ps += __shfl_xor(ps, 32);
        l_run[gi] = l_run[gi] * corr + ps;
        m_run[gi] = mnew;
        float c4[4];
        #pragma unroll
        for (int i = 0; i < 4; ++i) c4[i] = __shfl(corr, 4 * g + i);
        #pragma unroll
        for (int n = 0; n < 8; ++n)
          #pragma unroll
          for (int i = 0; i < 4; ++i) of[gi][n][i] *= c4[i];
        #pragma unroll
        for (int c = 0; c < 4; ++c) {
          ushort4 pw;
          pw.x = f2bf(pv[c * 4 + 0]); pw.y = f2bf(pv[c * 4 + 1]);
          pw.z = f2bf(pv[c * 4 + 2]); pw.w = f2bf(pv[c * 4 + 3]);
          *(ushort4*)(&Plds[w][lq * PSTR + c * 16 + 4 * g]) = pw;
        }
        short8 pf0 = *(const short8*)(&Plds[w][lq * PSTR + g * 8]);
        short8 pf1 = *(const short8*)(&Plds[w][lq * PSTR + 32 + g * 8]);
        __builtin_amdgcn_s_setprio(1);
        #pragma unroll
        for (int n = 0; n < 8; ++n) {
          int vr = n * 16 + lq;
          short8 vf0 = *(const short8*)(vldsC + vr * 128 + ((g * 16) ^ ((vr & 7) << 4)));
          short8 vf1 = *(const short8*)(vldsC + vr * 128 + ((64 + g * 16) ^ ((vr & 7) << 4)));
          of[gi][n] = __builtin_amdgcn_mfma_f32_16x16x32_bf16(pf0, vf0, of[gi][n], 0, 0, 0);
          of[gi][n] = __builtin_amdgcn_mfma_f32_16x16x32_bf16(pf1, vf1, of[gi][n], 0, 0, 0);
        }
        __builtin_amdgcn_s_setprio(0);
      }
    }
    __builtin_amdgcn_s_barrier();
  }
#undef AGLL

  #pragma unroll
  for (int gi = 0; gi < 2; ++gi) {
    float li[4];
    #pragma unroll
    for (int i = 0; i < 4; ++i) li[i] = 1.f / __shfl(l_run[gi], 4 * g + i);
    #pragma unroll
    for (int n = 0; n < 8; ++n)
      #pragma unroll
      for (int i = 0; i < 4; ++i) {
        int tok = qb + gi * 64 + w * 16 + 4 * g + i;
        ao[((size_t)(b * T_SEQ + tok) * (NH * HD)) + h * HD + n * 16 + lq] = f2bf(of[gi][n][i] * li[i]);
      }
  }
}

// ---------------- host ----------------
extern "C" void kernel_launch(void* const* d_in, const int* in_sizes, int n_in,
                              void* d_out, int out_size, void* d_ws, size_t ws_size,
                              hipStream_t stream) {
  const float* x   = (const float*)d_in[0];
  const float* rc  = (const float*)d_in[1];
  const float* rs  = (const float*)d_in[2];
  const float* ln1 = (const float*)d_in[3];
  const float* ln2 = (const float*)d_in[4];
  const float* wq  = (const float*)d_in[5];
  const float* wqb = (const float*)d_in[6];
  const float* wk  = (const float*)d_in[7];
  const float* wkb = (const float*)d_in[8];
  const float* wv  = (const float*)d_in[9];
  const float* wvb = (const float*)d_in[10];
  const float* wo  = (const float*)d_in[11];
  const float* wob = (const float*)d_in[12];
  const float* w1  = (const float*)d_in[13];
  const float* w1b = (const float*)d_in[14];
  const float* w2  = (const float*)d_in[15];
  const float* w2b = (const float*)d_in[16];

  char* ws = (char*)d_ws;
  size_t off = 0;
  auto alloc = [&](size_t bytes) {
    char* p = ws + off;
    off += (bytes + 255) & ~(size_t)255;
    return (void*)p;
  };
  const int M = BATCH * T_SEQ;  // 4096
  ushort_t* w1T  = (ushort_t*)alloc((size_t)11264 * 2048 * 2);
  ushort_t* w2T  = (ushort_t*)alloc((size_t)2048 * 5632 * 2);
  ushort_t* hbuf = (ushort_t*)alloc((size_t)M * 2048 * 2);    // h -> ao -> g
  ushort_t* vbufT= (ushort_t*)alloc((size_t)M * 512 * 2);     // V^T (b,hkv,d,t)
  float*    qkvb = (float*)alloc((size_t)QKVN * 4);
  // --- overlay region: [wqkvT | woT | qkbuf | extra] reused as act after attention ---
  size_t guStart = off;
  ushort_t* wqkvT = (ushort_t*)alloc((size_t)QKVN * 2048 * 2);
  ushort_t* woT  = (ushort_t*)alloc((size_t)2048 * 2048 * 2);
  ushort_t* qkbuf= (ushort_t*)alloc((size_t)M * QKS * 2);
  size_t actBytes = (size_t)M * ISZ * 2;
  size_t used = off - guStart;
  if (actBytes > used) alloc(actBytes - used);
  ushort_t* act = (ushort_t*)(ws + guStart);
  float* h1 = (float*)d_out;  // residual stream lives in d_out
  if (off > ws_size) return;

  // weight transpose-converts: wq|wk|wv -> one (3072, 2048) B^T; w1 permuted gate/up
  wconv_kernel<<<dim3(2048 / 32, 2048 / 32), 256, 0, stream>>>(wq, wqkvT, 2048, 2048);
  wconv_kernel<<<dim3(512 / 32, 2048 / 32), 256, 0, stream>>>(wk, wqkvT + (size_t)2048 * 2048, 2048, 512);
  wconv_kernel<<<dim3(512 / 32, 2048 / 32), 256, 0, stream>>>(wv, wqkvT + (size_t)QKS * 2048, 2048, 512);
  wconv_kernel<<<dim3(2048 / 32, 2048 / 32), 256, 0, stream>>>(wo, woT, 2048, 2048);
  wconvP_kernel<<<dim3(11264 / 32, 2048 / 32), 256, 0, stream>>>(w1, w1T, 2048, 11264);
  wconv_kernel<<<dim3(2048 / 32, 5632 / 32), 256, 0, stream>>>(w2, w2T, 5632, 2048);
  catbias_kernel<<<12, 256, 0, stream>>>(wqb, wkb, wvb, qkvb);

  rmsnorm_kernel<<<M, 256, 0, stream>>>(x, ln1, hbuf);

  // fused Q|K|V projection: rope'd q|k -> qkbuf, V -> vbufT (transposed), one dispatch
  gemm256_kernel<2><<<dim3(M / 256, QKVN / 256), 512, 0, stream>>>(
      hbuf, 2048, wqkvT, qkvb, qkbuf, M, QKVN, 2048, rc, rs, vbufT);

  attn_kernel<<<dim3(T_SEQ / QB, NH, BATCH), 256, 0, stream>>>(qkbuf, vbufT, hbuf);

  // Wo projection + residual (x) -> h1
  gemm128_kernel<<<dim3(M / 128, 2048 / 256), 512, 0, stream>>>(hbuf, 2048, woT, wob, x, h1, M, 2048, 2048);

  rmsnorm_kernel<<<M, 256, 0, stream>>>(h1, ln2, hbuf);  // g

  // W1 + fused SwiGLU (permuted weights), n-fastest grid -> act (M x 5632 bf16)
  gemm256_kernel<3><<<dim3(11264 / 256, M / 256), 512, 0, stream>>>(
      hbuf, 2048, w1T, w1b, act, M, 11264, 2048, nullptr, nullptr, nullptr);

  // W2 + residual (h1) -> d_out
  gemm128_kernel<<<dim3(M / 128, 2048 / 256), 512, 0, stream>>>(act, 5632, w2T, w2b, h1, (float*)d_out, M, 2048, 5632);

  (void)in_sizes; (void)n_in; (void)out_size;
}

// Round 18
// 591.813 us; speedup vs baseline: 2.5874x; 2.5874x over previous
//
#include <hip/hip_runtime.h>

#define T_SEQ 2048
#define DMODEL 2048
#define NH 16
#define NKV 4
#define HD 128
#define ISZ 5632
#define BATCH 2
#define QKS 2560   // q|k row stride in qkbuf
#define QKVN 3072  // fused q|k|v GEMM width

typedef unsigned short ushort_t;
typedef __attribute__((ext_vector_type(8))) short short8;
typedef __attribute__((ext_vector_type(4))) float f32x4;

__device__ __forceinline__ ushort_t f2bf(float f) {
  unsigned int u = __float_as_uint(f);
  unsigned int r = (u + 0x7FFFu + ((u >> 16) & 1u)) >> 16;
  return (ushort_t)r;
}
__device__ __forceinline__ float bf2f(ushort_t h) {
  return __uint_as_float(((unsigned int)h) << 16);
}

// ---------------- weight fp32 (K,N) -> bf16 transposed (N,K) ----------------
__global__ __launch_bounds__(256) void wconv_kernel(const float* __restrict__ W,
                                                    ushort_t* __restrict__ Wt,
                                                    int K, int N) {
  __shared__ float tile[32][33];
  const int n0 = blockIdx.x * 32, k0 = blockIdx.y * 32;
  const int t = threadIdx.x;
  const int r = t >> 3, c = (t & 7) * 4;
  float4 v = *(const float4*)(W + (size_t)(k0 + r) * N + n0 + c);
  tile[r][c + 0] = v.x; tile[r][c + 1] = v.y; tile[r][c + 2] = v.z; tile[r][c + 3] = v.w;
  __syncthreads();
  ushort4 o;
  o.x = f2bf(tile[c + 0][r]);
  o.y = f2bf(tile[c + 1][r]);
  o.z = f2bf(tile[c + 2][r]);
  o.w = f2bf(tile[c + 3][r]);
  *(ushort4*)(Wt + (size_t)(n0 + r) * K + k0 + c) = o;
}

// ---- w1 variant: output rows permuted to interleave gate/up in 16-col groups ----
// orig col G (gate) -> row' = (G>>4)*32 + (G&15); up G -> row' = (G>>4)*32 + 16 + (G&15)
__global__ __launch_bounds__(256) void wconvP_kernel(const float* __restrict__ W,
                                                     ushort_t* __restrict__ Wt,
                                                     int K, int N) {
  __shared__ float tile[32][33];
  const int n0 = blockIdx.x * 32, k0 = blockIdx.y * 32;
  const int t = threadIdx.x;
  const int r = t >> 3, c = (t & 7) * 4;
  float4 v = *(const float4*)(W + (size_t)(k0 + r) * N + n0 + c);
  tile[r][c + 0] = v.x; tile[r][c + 1] = v.y; tile[r][c + 2] = v.z; tile[r][c + 3] = v.w;
  __syncthreads();
  ushort4 o;
  o.x = f2bf(tile[c + 0][r]);
  o.y = f2bf(tile[c + 1][r]);
  o.z = f2bf(tile[c + 2][r]);
  o.w = f2bf(tile[c + 3][r]);
  int n = n0 + r;
  int np = (n < ISZ) ? ((n >> 4) << 5) + (n & 15)
                     : (((n - ISZ) >> 4) << 5) + 16 + ((n - ISZ) & 15);
  *(ushort4*)(Wt + (size_t)np * K + k0 + c) = o;
}

__global__ __launch_bounds__(256) void catbias_kernel(const float* __restrict__ a,
                                                      const float* __restrict__ b,
                                                      const float* __restrict__ c,
                                                      float* __restrict__ o) {
  int i = blockIdx.x * 256 + threadIdx.x;
  if (i < QKVN) o[i] = (i < 2048) ? a[i] : (i < QKS) ? b[i - 2048] : c[i - QKS];
}

// ---------------- RMSNorm (f32 in, bf16 out), D = 2048, block = 256 ----------------
__global__ __launch_bounds__(256) void rmsnorm_kernel(const float* __restrict__ x,
                                                      const float* __restrict__ w,
                                                      ushort_t* __restrict__ out) {
  const int row = blockIdx.x;
  const int t = threadIdx.x;
  const float* xr = x + (size_t)row * DMODEL;
  float4 v0 = *(const float4*)(xr + t * 4);
  float4 v1 = *(const float4*)(xr + 1024 + t * 4);
  float ss = v0.x * v0.x + v0.y * v0.y + v0.z * v0.z + v0.w * v0.w +
             v1.x * v1.x + v1.y * v1.y + v1.z * v1.z + v1.w * v1.w;
  #pragma unroll
  for (int m = 1; m < 64; m <<= 1) ss += __shfl_xor(ss, m);
  __shared__ float red[4];
  if ((t & 63) == 0) red[t >> 6] = ss;
  __syncthreads();
  float tot = red[0] + red[1] + red[2] + red[3];
  float rinv = rsqrtf(tot * (1.0f / DMODEL) + 1e-5f);
  float4 w0 = *(const float4*)(w + t * 4);
  float4 w1 = *(const float4*)(w + 1024 + t * 4);
  ushort4 o0, o1;
  o0.x = f2bf(v0.x * rinv * w0.x); o0.y = f2bf(v0.y * rinv * w0.y);
  o0.z = f2bf(v0.z * rinv * w0.z); o0.w = f2bf(v0.w * rinv * w0.w);
  o1.x = f2bf(v1.x * rinv * w1.x); o1.y = f2bf(v1.y * rinv * w1.y);
  o1.z = f2bf(v1.z * rinv * w1.z); o1.w = f2bf(v1.w * rinv * w1.w);
  *(ushort4*)(out + (size_t)row * DMODEL + t * 4) = o0;
  *(ushort4*)(out + (size_t)row * DMODEL + 1024 + t * 4) = o1;
}

// ================= 256x256 GEMM, double-buffered free-running pipeline ==================
// MODE 0: bf16 out = A@B + bias.              Grid (N/256, M/256) — n-fastest.
// MODE 2: QKV projection.                     Grid (M/256, N/256) — m-fastest.
//         c<QKS: rope(A@B+bias) -> outp; c>=QKS: V^T (b,hkv,d,t) -> outp2.
// MODE 3: W1+SwiGLU (permuted gate/up weights). Grid (N/256, M/256) — n-fastest.
//         nf even=gate, nf odd=up; act[r][G] = silu(g+bg)*(u+bu), bias unpermuted lookup.
template <int MODE>
__global__ __launch_bounds__(512, 2)
void gemm256_kernel(const ushort_t* __restrict__ A, int lda,
                    const ushort_t* __restrict__ Bt,
                    const float* __restrict__ bias, void* __restrict__ outp,
                    int M, int N, int K,
                    const float* __restrict__ rc, const float* __restrict__ rs,
                    ushort_t* __restrict__ outp2) {
  __shared__ ushort_t lds[65536];  // 128 KiB = 2 bufs x 64KB
  const int tid = threadIdx.x;
  const int wid = tid >> 6, lane = tid & 63;
  const int lq = lane & 15, g = lane >> 4;
  const int wm = wid >> 2, wn = wid & 3;
  const int m0 = (MODE == 2 ? blockIdx.x : blockIdx.y) * 256;
  const int n0 = (MODE == 2 ? blockIdx.y : blockIdx.x) * 256;
  const int NT = K >> 6;

  const char* ldsc = (const char*)lds;
  const int c0 = ((g ^ (lq & 3)) << 4) | (((lq >> 2) & 1) << 6);
  const int rbA = wm * 8192 + lq * 128 + c0;
  const int rbAx = rbA ^ 64;
  const int rbB = 32768 + wn * 4096 + lq * 128 + c0;
  const int rbBx = rbB ^ 64;

  const int l3 = lane >> 3;
  const int clog = ((lane & 7) ^ l3) << 4;
  const int s0 = wid * 16 + l3, s1 = s0 + 8;
  const int rA0 = (s0 & 63) + ((s0 >> 6) << 7);
  const int rA0b = (s1 & 63) + ((s1 >> 6) << 7);
  const int rB0 = ((s0 >> 5) << 6) + (s0 & 31);
  const int rB0b = ((s1 >> 5) << 6) + (s1 & 31);
  const char* pA0a = (const char*)A + (size_t)(m0 + rA0) * (lda * 2) + clog;
  const char* pA0b = (const char*)A + (size_t)(m0 + rA0b) * (lda * 2) + clog;
  const char* pA1a = pA0a + (size_t)64 * (lda * 2);
  const char* pA1b = pA0b + (size_t)64 * (lda * 2);
  const char* pB0a = (const char*)Bt + (size_t)(n0 + rB0) * (K * 2) + clog;
  const char* pB0b = (const char*)Bt + (size_t)(n0 + rB0b) * (K * 2) + clog;
  const char* pB1a = pB0a + (size_t)32 * (K * 2);
  const char* pB1b = pB0b + (size_t)32 * (K * 2);
  ushort_t* sd = lds + wid * 1024;

#define GLL(SRC, DOFF)                                                        \
  __builtin_amdgcn_global_load_lds(                                           \
      (const __attribute__((address_space(1))) void*)(SRC),                   \
      (__attribute__((address_space(3))) void*)(sd + (DOFF)), 16, 0, 0)
#define STG_ALL(PB)                                                           \
  {                                                                           \
    GLL(pA0a, (PB)*32768 + 0);     GLL(pA0b, (PB)*32768 + 512);               \
    GLL(pB0a, (PB)*32768 + 16384); GLL(pB0b, (PB)*32768 + 16896);             \
    GLL(pB1a, (PB)*32768 + 24576); GLL(pB1b, (PB)*32768 + 25088);             \
    GLL(pA1a, (PB)*32768 + 8192);  GLL(pA1b, (PB)*32768 + 8704);              \
    pA0a += 128; pA0b += 128; pA1a += 128; pA1b += 128;                       \
    pB0a += 128; pB0b += 128; pB1a += 128; pB1b += 128;                       \
  }

  f32x4 acc[8][4] = {};

#define TILE(P, DOST)                                                         \
  {                                                                           \
    asm volatile("s_waitcnt vmcnt(0)" ::: "memory");                          \
    __builtin_amdgcn_s_barrier();                                             \
    if (DOST) STG_ALL((P) ^ 1)                                                \
    short8 aA0[4][2], aA1[4][2], bb0[2][2], bb1[2][2];                        \
    _Pragma("unroll") for (int mi = 0; mi < 4; ++mi) {                        \
      aA0[mi][0] = *(const short8*)(ldsc + (P)*65536 + rbA + mi * 2048);      \
      aA0[mi][1] = *(const short8*)(ldsc + (P)*65536 + rbAx + mi * 2048);     \
    }                                                                         \
    _Pragma("unroll") for (int nj = 0; nj < 2; ++nj) {                        \
      bb0[nj][0] = *(const short8*)(ldsc + (P)*65536 + rbB + nj * 2048);      \
      bb0[nj][1] = *(const short8*)(ldsc + (P)*65536 + rbBx + nj * 2048);     \
    }                                                                         \
    _Pragma("unroll") for (int mi = 0; mi < 4; ++mi)                          \
      _Pragma("unroll") for (int nj = 0; nj < 2; ++nj) {                      \
        acc[mi][nj] = __builtin_amdgcn_mfma_f32_16x16x32_bf16(aA0[mi][0], bb0[nj][0], acc[mi][nj], 0, 0, 0); \
        acc[mi][nj] = __builtin_amdgcn_mfma_f32_16x16x32_bf16(aA0[mi][1], bb0[nj][1], acc[mi][nj], 0, 0, 0); \
      }                                                                       \
    _Pragma("unroll") for (int nj = 0; nj < 2; ++nj) {                        \
      bb1[nj][0] = *(const short8*)(ldsc + (P)*65536 + rbB + 16384 + nj * 2048);  \
      bb1[nj][1] = *(const short8*)(ldsc + (P)*65536 + rbBx + 16384 + nj * 2048); \
    }                                                                         \
    _Pragma("unroll") for (int mi = 0; mi < 4; ++mi)                          \
      _Pragma("unroll") for (int nj = 0; nj < 2; ++nj) {                      \
        acc[mi][2 + nj] = __builtin_amdgcn_mfma_f32_16x16x32_bf16(aA0[mi][0], bb1[nj][0], acc[mi][2 + nj], 0, 0, 0); \
        acc[mi][2 + nj] = __builtin_amdgcn_mfma_f32_16x16x32_bf16(aA0[mi][1], bb1[nj][1], acc[mi][2 + nj], 0, 0, 0); \
      }                                                                       \
    _Pragma("unroll") for (int mi = 0; mi < 4; ++mi) {                        \
      aA1[mi][0] = *(const short8*)(ldsc + (P)*65536 + rbA + 16384 + mi * 2048);  \
      aA1[mi][1] = *(const short8*)(ldsc + (P)*65536 + rbAx + 16384 + mi * 2048); \
    }                                                                         \
    _Pragma("unroll") for (int mi = 0; mi < 4; ++mi)                          \
      _Pragma("unroll") for (int nj = 0; nj < 2; ++nj) {                      \
        acc[4 + mi][nj] = __builtin_amdgcn_mfma_f32_16x16x32_bf16(aA1[mi][0], bb0[nj][0], acc[4 + mi][nj], 0, 0, 0); \
        acc[4 + mi][nj] = __builtin_amdgcn_mfma_f32_16x16x32_bf16(aA1[mi][1], bb0[nj][1], acc[4 + mi][nj], 0, 0, 0); \
      }                                                                       \
    _Pragma("unroll") for (int mi = 0; mi < 4; ++mi)                          \
      _Pragma("unroll") for (int nj = 0; nj < 2; ++nj) {                      \
        acc[4 + mi][2 + nj] = __builtin_amdgcn_mfma_f32_16x16x32_bf16(aA1[mi][0], bb1[nj][0], acc[4 + mi][2 + nj], 0, 0, 0); \
        acc[4 + mi][2 + nj] = __builtin_amdgcn_mfma_f32_16x16x32_bf16(aA1[mi][1], bb1[nj][1], acc[4 + mi][2 + nj], 0, 0, 0); \
      }                                                                       \
  }

  STG_ALL(0)
  for (int it = 0; it + 2 < NT; it += 2) {
    TILE(0, true)
    TILE(1, true)
  }
  TILE(0, true)
  TILE(1, false)
#undef TILE
#undef GLL
#undef STG_ALL

  if (MODE == 3) {
    // gate/up interleaved epilogue: pairs (nf, nf+1), output col G = (c>>5)<<4 | (c&15)
    #pragma unroll
    for (int nf = 0; nf < 4; nf += 2) {
      int cg = n0 + wn * 64 + nf * 16 + lq;    // permuted gate col
      int G = ((cg >> 5) << 4) | (cg & 15);    // original gate index (= act col)
      float bg = bias[G];
      float bu = bias[ISZ + G];
      #pragma unroll
      for (int mf = 0; mf < 8; ++mf) {
        #pragma unroll
        for (int i = 0; i < 4; ++i) {
          int r = m0 + wm * 128 + mf * 16 + g * 4 + i;
          float gv = acc[mf][nf][i] + bg;
          float uv = acc[mf][nf + 1][i] + bu;
          float sl = gv / (1.f + __expf(-gv));
          ((ushort_t*)outp)[(size_t)r * ISZ + G] = f2bf(sl * uv);
        }
      }
    }
  } else {
    #pragma unroll
    for (int nf = 0; nf < 4; ++nf) {
      int c = n0 + wn * 64 + nf * 16 + lq;
      float bb = bias[c];
      int d = (c & (HD - 1)) >> 1;      // rope dim index (MODE 2, q|k region)
      #pragma unroll
      for (int mf = 0; mf < 8; ++mf) {
        #pragma unroll
        for (int i = 0; i < 4; ++i) {
          int r = m0 + wm * 128 + mf * 16 + g * 4 + i;
          float av = acc[mf][nf][i] + bb;
          if (MODE == 2) {
            if (c < QKS) {
              float pr = __shfl_xor(av, 1);
              int t = r & (T_SEQ - 1);
              float co = rc[t * 64 + d];
              float si = rs[t * 64 + d];
              float ov = (lq & 1) ? (pr * si + av * co) : (av * co - pr * si);
              ((ushort_t*)outp)[(size_t)r * QKS + c] = f2bf(ov);
            } else {
              int cv = c - QKS;
              int hk = cv >> 7, dd = cv & (HD - 1);
              int b2 = r >> 11, t2 = r & (T_SEQ - 1);
              outp2[((size_t)(b2 * NKV + hk) * HD + dd) * T_SEQ + t2] = f2bf(av);
            }
          } else {
            ((ushort_t*)outp)[(size_t)r * N + c] = f2bf(av);
          }
        }
      }
    }
  }
}

// ================= 128x256 GEMM (8 waves, 64x64 wave-tiles), f32 res-add epilogue ========
__global__ __launch_bounds__(512, 1)
void gemm128_kernel(const ushort_t* __restrict__ A, int lda,
                    const ushort_t* __restrict__ Bt,
                    const float* __restrict__ bias, const float* __restrict__ res,
                    float* __restrict__ outp, int M, int N, int K) {
  __shared__ ushort_t lds[49152];  // 96KB = 2 bufs x 48KB
  const int tid = threadIdx.x;
  const int wid = tid >> 6, lane = tid & 63;
  const int lq = lane & 15, g = lane >> 4;
  const int wm = wid & 1, wn = wid >> 1;
  const int m0 = blockIdx.x * 128, n0 = blockIdx.y * 256;
  const int NT = K >> 6;

  const char* ldsc = (const char*)lds;
  const int c0 = ((g ^ (lq & 3)) << 4) | (((lq >> 2) & 1) << 6);
  const int rbA = wm * 8192 + lq * 128 + c0;
  const int rbAx = rbA ^ 64;
  const int rbB = 16384 + wn * 8192 + lq * 128 + c0;
  const int rbBx = rbB ^ 64;

  const char* pA[2];
  const char* pB[4];
  #pragma unroll
  for (int j = 0; j < 2; ++j) {
    int pb = (wid * 2 + j) * 1024 + lane * 16;
    int ob = pb ^ (((pb >> 7) & 7) << 4);
    pA[j] = (const char*)A + (size_t)(m0 + (ob >> 7)) * (lda * 2) + (ob & 127);
  }
  #pragma unroll
  for (int j = 0; j < 4; ++j) {
    int pb = (wid * 4 + j) * 1024 + lane * 16;
    int ob = pb ^ (((pb >> 7) & 7) << 4);
    pB[j] = (const char*)Bt + (size_t)(n0 + (ob >> 7)) * (K * 2) + (ob & 127);
  }
  ushort_t* sdA = lds + wid * 1024;
  ushort_t* sdB = lds + 8192 + wid * 2048;

#define GLL1(SRC, DST)                                                        \
  __builtin_amdgcn_global_load_lds(                                           \
      (const __attribute__((address_space(1))) void*)(SRC),                   \
      (__attribute__((address_space(3))) void*)(DST), 16, 0, 0)
#define STG128(PB)                                                            \
  {                                                                           \
    GLL1(pA[0], sdA + (PB)*24576 + 0);   GLL1(pA[1], sdA + (PB)*24576 + 512); \
    GLL1(pB[0], sdB + (PB)*24576 + 0);   GLL1(pB[1], sdB + (PB)*24576 + 512); \
    GLL1(pB[2], sdB + (PB)*24576 + 1024); GLL1(pB[3], sdB + (PB)*24576 + 1536); \
    pA[0] += 128; pA[1] += 128;                                               \
    pB[0] += 128; pB[1] += 128; pB[2] += 128; pB[3] += 128;                   \
  }

  f32x4 acc[4][4] = {};

#define TILE128(P, TCUR)                                                      \
  {                                                                           \
    asm volatile("s_waitcnt vmcnt(0)" ::: "memory");                          \
    __builtin_amdgcn_s_barrier();                                             \
    if ((TCUR) + 1 < NT) STG128((P) ^ 1)                                      \
    short8 aA[4][2], bb[4][2];                                                \
    _Pragma("unroll") for (int mi = 0; mi < 4; ++mi) {                        \
      aA[mi][0] = *(const short8*)(ldsc + (P)*49152 + rbA + mi * 2048);       \
      aA[mi][1] = *(const short8*)(ldsc + (P)*49152 + rbAx + mi * 2048);      \
    }                                                                         \
    _Pragma("unroll") for (int nj = 0; nj < 4; ++nj) {                        \
      bb[nj][0] = *(const short8*)(ldsc + (P)*49152 + rbB + nj * 2048);       \
      bb[nj][1] = *(const short8*)(ldsc + (P)*49152 + rbBx + nj * 2048);      \
    }                                                                         \
    _Pragma("unroll") for (int mi = 0; mi < 4; ++mi)                          \
      _Pragma("unroll") for (int nj = 0; nj < 4; ++nj) {                      \
        acc[mi][nj] = __builtin_amdgcn_mfma_f32_16x16x32_bf16(aA[mi][0], bb[nj][0], acc[mi][nj], 0, 0, 0); \
        acc[mi][nj] = __builtin_amdgcn_mfma_f32_16x16x32_bf16(aA[mi][1], bb[nj][1], acc[mi][nj], 0, 0, 0); \
      }                                                                       \
  }

  STG128(0)
  for (int t = 0; t < NT; t += 2) {
    TILE128(0, t)
    TILE128(1, t + 1)
  }
#undef TILE128
#undef GLL1
#undef STG128

  #pragma unroll
  for (int nf = 0; nf < 4; ++nf) {
    int c = n0 + wn * 64 + nf * 16 + lq;
    float bb = bias[c];
    #pragma unroll
    for (int mf = 0; mf < 4; ++mf) {
      #pragma unroll
      for (int i = 0; i < 4; ++i) {
        int r = m0 + wm * 64 + mf * 16 + g * 4 + i;
        size_t oidx = (size_t)r * N + c;
        outp[oidx] = res[oidx] + acc[mf][nf][i] + bb;
      }
    }
  }
}

// ---------------- Flash attention, GQA causal, QB=128, GLL-staged swizzled K/V ----------
#define QB 128
#define KB 64
#define PSTR 72

__global__ __launch_bounds__(256, 2)
void attn_kernel(const ushort_t* __restrict__ qk, const ushort_t* __restrict__ vT,
                 ushort_t* __restrict__ ao) {
  __shared__ ushort_t Klds[KB * 128];
  __shared__ ushort_t Vlds[HD * 64];
  __shared__ ushort_t Plds[4][16 * PSTR];

  const int tid = threadIdx.x;
  const int w = tid >> 6, lane = tid & 63;
  const int lq = lane & 15, g = lane >> 4;
  const int nqb = T_SEQ / QB;  // 16
  const int xq = blockIdx.x;
  const int qi = (xq & 1) ? (nqb - 1 - (xq >> 1)) : (xq >> 1);
  const int qb = qi * QB;
  const int h = blockIdx.y;
  const int b = blockIdx.z;
  const int hkv = h >> 2;
  const float scale = 0.08838834764831845f;

  short8 qf[2][4];
  #pragma unroll
  for (int gi = 0; gi < 2; ++gi) {
    const ushort_t* qrow = qk + ((size_t)(b * T_SEQ + qb + gi * 64 + w * 16 + lq) * QKS) + h * HD;
    #pragma unroll
    for (int ks = 0; ks < 4; ++ks) qf[gi][ks] = *(const short8*)(qrow + ks * 32 + g * 8);
  }

  f32x4 of[2][8] = {};
  float m_run[2] = {-1e30f, -1e30f};
  float l_run[2] = {0.f, 0.f};

  const char* kbaseC = (const char*)(qk + (size_t)b * T_SEQ * QKS + 2048 + hkv * HD);
  const char* vbaseC = (const char*)(vT + (size_t)(b * NKV + hkv) * HD * T_SEQ);
  const char* pK[4];
  const char* pV[4];
  #pragma unroll
  for (int j = 0; j < 4; ++j) {
    int krow = w * 16 + j * 4 + (lane >> 4);
    int kcol = ((lane & 15) * 16) ^ ((krow & 7) << 4);
    pK[j] = kbaseC + (size_t)krow * (QKS * 2) + kcol;
    int vrow = w * 32 + j * 8 + (lane >> 3);
    int vcol = ((lane & 7) * 16) ^ ((vrow & 7) << 4);
    pV[j] = vbaseC + (size_t)vrow * (T_SEQ * 2) + vcol;
  }
  ushort_t* kdst = Klds + w * 2048;
  ushort_t* vdst = Vlds + w * 2048;
  const char* kldsC = (const char*)Klds;
  const char* vldsC = (const char*)Vlds;

#define AGLL(SRC, DST)                                                        \
  __builtin_amdgcn_global_load_lds(                                           \
      (const __attribute__((address_space(1))) void*)(SRC),                   \
      (__attribute__((address_space(3))) void*)(DST), 16, 0, 0)

  const int nt = qb / KB + 2;
  for (int ti = 0; ti < nt; ++ti) {
    const int kt = ti * KB;
    #pragma unroll
    for (int j = 0; j < 4; ++j) {
      AGLL(pK[j], kdst + j * 512);
      AGLL(pV[j], vdst + j * 512);
      pK[j] += (size_t)KB * (QKS * 2);
      pV[j] += KB * 2;
    }
    asm volatile("s_waitcnt vmcnt(0)" ::: "memory");
    __builtin_amdgcn_s_barrier();

    #pragma unroll
    for (int gi = 0; gi < 2; ++gi) {
      const int qw = qb + gi * 64 + w * 16;
      if (kt <= qw + 15) {
        f32x4 s[4] = {};
        __builtin_amdgcn_s_setprio(1);
        #pragma unroll
        for (int c = 0; c < 4; ++c) {
          int krow = c * 16 + lq;
          #pragma unroll
          for (int ks = 0; ks < 4; ++ks) {
            short8 kf = *(const short8*)(kldsC + krow * 256 + (((ks * 64) + g * 16) ^ ((krow & 7) << 4)));
            s[c] = __builtin_amdgcn_mfma_f32_16x16x32_bf16(kf, qf[gi][ks], s[c], 0, 0, 0);
          }
        }
        __builtin_amdgcn_s_setprio(0);
        const int qg = qw + lq;
        float sv[16];
        #pragma unroll
        for (int c = 0; c < 4; ++c)
          #pragma unroll
          for (int i = 0; i < 4; ++i) {
            int kvg = kt + c * 16 + 4 * g + i;
            float xx = s[c][i] * scale;
            sv[c * 4 + i] = (kvg > qg) ? -1e30f : xx;
          }
        float tmax = sv[0];
        #pragma unroll
        for (int j = 1; j < 16; ++j) tmax = fmaxf(tmax, sv[j]);
        tmax = fmaxf(tmax, __shfl_xor(tmax, 16));
        tmax = fmaxf(tmax, __shfl_xor(tmax, 32));
        float mnew = fmaxf(m_run[gi], tmax);
        float corr = __expf(m_run[gi] - mnew);
        float pv[16];
        float ps = 0.f;
        #pragma unroll
        for (int j = 0; j < 16; ++j) { pv[j] = __expf(sv[j] - mnew); ps += pv[j]; }
        ps += __shfl_xor(ps, 16);
        ps += __shfl_xor(ps, 32);
        l_run[gi] = l_run[gi] * corr + ps;
        m_run[gi] = mnew;
        float c4[4];
        #pragma unroll
        for (int i = 0; i < 4; ++i) c4[i] = __shfl(corr, 4 * g + i);
        #pragma unroll
        for (int n = 0; n < 8; ++n)
          #pragma unroll
          for (int i = 0; i < 4; ++i) of[gi][n][i] *= c4[i];
        #pragma unroll
        for (int c = 0; c < 4; ++c) {
          ushort4 pw;
          pw.x = f2bf(pv[c * 4 + 0]); pw.y = f2bf(pv[c * 4 + 1]);
          pw.z = f2bf(pv[c * 4 + 2]); pw.w = f2bf(pv[c * 4 + 3]);
          *(ushort4*)(&Plds[w][lq * PSTR + c * 16 + 4 * g]) = pw;
        }
        short8 pf0 = *(const short8*)(&Plds[w][lq * PSTR + g * 8]);
        short8 pf1 = *(const short8*)(&Plds[w][lq * PSTR + 32 + g * 8]);
        __builtin_amdgcn_s_setprio(1);
        #pragma unroll
        for (int n = 0; n < 8; ++n) {
          int vr = n * 16 + lq;
          short8 vf0 = *(const short8*)(vldsC + vr * 128 + ((g * 16) ^ ((vr & 7) << 4)));
          short8 vf1 = *(const short8*)(vldsC + vr * 128 + ((64 + g * 16) ^ ((vr & 7) << 4)));
          of[gi][n] = __builtin_amdgcn_mfma_f32_16x16x32_bf16(pf0, vf0, of[gi][n], 0, 0, 0);
          of[gi][n] = __builtin_amdgcn_mfma_f32_16x16x32_bf16(pf1, vf1, of[gi][n], 0, 0, 0);
        }
        __builtin_amdgcn_s_setprio(0);
      }
    }
    __builtin_amdgcn_s_barrier();
  }
#undef AGLL

  #pragma unroll
  for (int gi = 0; gi < 2; ++gi) {
    float li[4];
    #pragma unroll
    for (int i = 0; i < 4; ++i) li[i] = 1.f / __shfl(l_run[gi], 4 * g + i);
    #pragma unroll
    for (int n = 0; n < 8; ++n)
      #pragma unroll
      for (int i = 0; i < 4; ++i) {
        int tok = qb + gi * 64 + w * 16 + 4 * g + i;
        ao[((size_t)(b * T_SEQ + tok) * (NH * HD)) + h * HD + n * 16 + lq] = f2bf(of[gi][n][i] * li[i]);
      }
  }
}

// ---------------- host ----------------
extern "C" void kernel_launch(void* const* d_in, const int* in_sizes, int n_in,
                              void* d_out, int out_size, void* d_ws, size_t ws_size,
                              hipStream_t stream) {
  const float* x   = (const float*)d_in[0];
  const float* rc  = (const float*)d_in[1];
  const float* rs  = (const float*)d_in[2];
  const float* ln1 = (const float*)d_in[3];
  const float* ln2 = (const float*)d_in[4];
  const float* wq  = (const float*)d_in[5];
  const float* wqb = (const float*)d_in[6];
  const float* wk  = (const float*)d_in[7];
  const float* wkb = (const float*)d_in[8];
  const float* wv  = (const float*)d_in[9];
  const float* wvb = (const float*)d_in[10];
  const float* wo  = (const float*)d_in[11];
  const float* wob = (const float*)d_in[12];
  const float* w1  = (const float*)d_in[13];
  const float* w1b = (const float*)d_in[14];
  const float* w2  = (const float*)d_in[15];
  const float* w2b = (const float*)d_in[16];

  char* ws = (char*)d_ws;
  size_t off = 0;
  auto alloc = [&](size_t bytes) {
    char* p = ws + off;
    off += (bytes + 255) & ~(size_t)255;
    return (void*)p;
  };
  const int M = BATCH * T_SEQ;  // 4096
  ushort_t* w1T  = (ushort_t*)alloc((size_t)11264 * 2048 * 2);
  ushort_t* w2T  = (ushort_t*)alloc((size_t)2048 * 5632 * 2);
  ushort_t* hbuf = (ushort_t*)alloc((size_t)M * 2048 * 2);    // h -> ao -> g
  ushort_t* vbufT= (ushort_t*)alloc((size_t)M * 512 * 2);     // V^T (b,hkv,d,t)
  float*    qkvb = (float*)alloc((size_t)QKVN * 4);
  // --- overlay region: [wqkvT | woT | qkbuf | extra] reused as act after attention ---
  size_t guStart = off;
  ushort_t* wqkvT = (ushort_t*)alloc((size_t)QKVN * 2048 * 2);
  ushort_t* woT  = (ushort_t*)alloc((size_t)2048 * 2048 * 2);
  ushort_t* qkbuf= (ushort_t*)alloc((size_t)M * QKS * 2);
  size_t actBytes = (size_t)M * ISZ * 2;
  size_t used = off - guStart;
  if (actBytes > used) alloc(actBytes - used);
  ushort_t* act = (ushort_t*)(ws + guStart);
  float* h1 = (float*)d_out;  // residual stream lives in d_out
  if (off > ws_size) return;

  // weight transpose-converts: wq|wk|wv -> one (3072, 2048) B^T; w1 permuted gate/up
  wconv_kernel<<<dim3(2048 / 32, 2048 / 32), 256, 0, stream>>>(wq, wqkvT, 2048, 2048);
  wconv_kernel<<<dim3(512 / 32, 2048 / 32), 256, 0, stream>>>(wk, wqkvT + (size_t)2048 * 2048, 2048, 512);
  wconv_kernel<<<dim3(512 / 32, 2048 / 32), 256, 0, stream>>>(wv, wqkvT + (size_t)QKS * 2048, 2048, 512);
  wconv_kernel<<<dim3(2048 / 32, 2048 / 32), 256, 0, stream>>>(wo, woT, 2048, 2048);
  wconvP_kernel<<<dim3(11264 / 32, 2048 / 32), 256, 0, stream>>>(w1, w1T, 2048, 11264);
  wconv_kernel<<<dim3(2048 / 32, 5632 / 32), 256, 0, stream>>>(w2, w2T, 5632, 2048);
  catbias_kernel<<<12, 256, 0, stream>>>(wqb, wkb, wvb, qkvb);

  rmsnorm_kernel<<<M, 256, 0, stream>>>(x, ln1, hbuf);

  // fused Q|K|V projection: rope'd q|k -> qkbuf, V -> vbufT (transposed), one dispatch
  gemm256_kernel<2><<<dim3(M / 256, QKVN / 256), 512, 0, stream>>>(
      hbuf, 2048, wqkvT, qkvb, qkbuf, M, QKVN, 2048, rc, rs, vbufT);

  attn_kernel<<<dim3(T_SEQ / QB, NH, BATCH), 256, 0, stream>>>(qkbuf, vbufT, hbuf);

  // Wo projection + residual (x) -> h1
  gemm128_kernel<<<dim3(M / 128, 2048 / 256), 512, 0, stream>>>(hbuf, 2048, woT, wob, x, h1, M, 2048, 2048);

  rmsnorm_kernel<<<M, 256, 0, stream>>>(h1, ln2, hbuf);  // g

  // W1 + fused SwiGLU (permuted weights), n-fastest grid -> act (M x 5632 bf16)
  gemm256_kernel<3><<<dim3(11264 / 256, M / 256), 512, 0, stream>>>(
      hbuf, 2048, w1T, w1b, act, M, 11264, 2048, nullptr, nullptr, nullptr);

  // W2 + residual (h1) -> d_out
  gemm128_kernel<<<dim3(M / 128, 2048 / 256), 512, 0, stream>>>(act, 5632, w2T, w2b, h1, (float*)d_out, M, 2048, 5632);

  (void)in_sizes; (void)n_in; (void)out_size;
}